// Round 1
// baseline (360.918 us; speedup 1.0000x reference)
//
#include <hip/hip_runtime.h>
#include <hip/hip_bf16.h>

#define D 128
#define NPB 64        // nodes per block in projection kernel
#define CHUNK 1024    // max edges cached per LDS chunk in aggregate kernel

// ---------------------------------------------------------------------------
// K1: per-node projection.  proj[n][:] = feats[n][:] @ W[wrow:wrow+128][:],
//     att[n] = feats[n][:] . w_att[wrow:wrow+128]
// block = 256 threads, NPB=64 nodes per block, register tile 8 nodes x 4 cols
// ---------------------------------------------------------------------------
__global__ void __launch_bounds__(256)
node_proj_kernel(const float* __restrict__ feats,    // [n_nodes,128]
                 const float* __restrict__ w_embed,  // [258,128]
                 const float* __restrict__ w_att,    // [258]
                 int wrow, int n_nodes,
                 float* __restrict__ proj,           // [n_nodes,128]
                 float* __restrict__ att)            // [n_nodes]
{
    __shared__ float s_feat[NPB][D + 1];   // +1 pad: bank-conflict-free column reads
    __shared__ float s_att[NPB][4];

    const int node0 = blockIdx.x * NPB;
    const int tid = threadIdx.x;

    // stage feature tile (coalesced)
    for (int i = tid; i < NPB * D; i += 256) {
        int r = i >> 7, c = i & 127;
        int n = node0 + r;
        s_feat[r][c] = (n < n_nodes) ? feats[n * D + c] : 0.f;
    }
    __syncthreads();

    const int tx = tid & 31;   // column group: cols 4*tx .. 4*tx+3
    const int ty = tid >> 5;   // node group:   nodes ty*8 .. ty*8+7

    float acc[8][4];
#pragma unroll
    for (int i = 0; i < 8; ++i)
#pragma unroll
        for (int j = 0; j < 4; ++j) acc[i][j] = 0.f;

    for (int k = 0; k < D; ++k) {
        float4 w = *reinterpret_cast<const float4*>(&w_embed[(wrow + k) * D + tx * 4]);
#pragma unroll
        for (int i = 0; i < 8; ++i) {
            float f = s_feat[ty * 8 + i][k];
            acc[i][0] += f * w.x;
            acc[i][1] += f * w.y;
            acc[i][2] += f * w.z;
            acc[i][3] += f * w.w;
        }
    }

#pragma unroll
    for (int i = 0; i < 8; ++i) {
        int n = node0 + ty * 8 + i;
        if (n < n_nodes) {
            float4 v = make_float4(acc[i][0], acc[i][1], acc[i][2], acc[i][3]);
            *reinterpret_cast<float4*>(&proj[n * D + tx * 4]) = v;
        }
    }

    // attention scalar: 256 threads = 64 nodes x 4 k-quarters
    const int na = tid & 63;
    const int kq = tid >> 6;
    float p = 0.f;
#pragma unroll 8
    for (int k = kq * 32; k < kq * 32 + 32; ++k)
        p += s_feat[na][k] * w_att[wrow + k];
    s_att[na][kq] = p;
    __syncthreads();
    if (tid < NPB) {
        int n = node0 + tid;
        if (n < n_nodes)
            att[n] = s_att[tid][0] + s_att[tid][1] + s_att[tid][2] + s_att[tid][3];
    }
}

// ---------------------------------------------------------------------------
// K2: histogram of edge destinations
// ---------------------------------------------------------------------------
__global__ void hist_kernel(const int* __restrict__ edst, int* __restrict__ counts,
                            int n_edge)
{
    int e = blockIdx.x * blockDim.x + threadIdx.x;
    if (e < n_edge) atomicAdd(&counts[edst[e]], 1);
}

// ---------------------------------------------------------------------------
// K3: single-block exclusive scan (1024 threads, 8 items/thread per tile)
//     writes offsets[0..n] and cursor[0..n-1] (= offsets copy for scatter)
// ---------------------------------------------------------------------------
__global__ void __launch_bounds__(1024)
scan_kernel(const int* __restrict__ counts, int* __restrict__ offsets,
            int* __restrict__ cursor, int n)
{
    const int T = 1024, IT = 8, TILE = T * IT;
    __shared__ int s_wsum[16];
    __shared__ int s_carry;
    const int tid = threadIdx.x;
    const int lane = tid & 63, wid = tid >> 6;
    if (tid == 0) s_carry = 0;
    __syncthreads();

    for (int base = 0; base < n; base += TILE) {
        int vals[IT];
        int tsum = 0;
#pragma unroll
        for (int i = 0; i < IT; ++i) {
            int idx = base + tid * IT + i;
            vals[i] = (idx < n) ? counts[idx] : 0;
            tsum += vals[i];
        }
        // inclusive wave scan of per-thread sums
        int x = tsum;
#pragma unroll
        for (int off = 1; off < 64; off <<= 1) {
            int y = __shfl_up(x, off);
            if (lane >= off) x += y;
        }
        if (lane == 63) s_wsum[wid] = x;
        __syncthreads();
        if (tid < 16) {
            int w = s_wsum[tid];
#pragma unroll
            for (int off = 1; off < 16; off <<= 1) {
                int y = __shfl_up(w, off);
                if (tid >= off) w += y;
            }
            s_wsum[tid] = w;   // inclusive scan of wave sums
        }
        __syncthreads();
        int carry = s_carry;
        int wave_excl = (wid == 0) ? 0 : s_wsum[wid - 1];
        int run = carry + wave_excl + (x - tsum);
#pragma unroll
        for (int i = 0; i < IT; ++i) {
            int idx = base + tid * IT + i;
            if (idx < n) { offsets[idx] = run; cursor[idx] = run; }
            run += vals[i];
        }
        __syncthreads();
        if (tid == 0) s_carry = carry + s_wsum[15];
        __syncthreads();
    }
    if (tid == 0) offsets[n] = s_carry;
}

// ---------------------------------------------------------------------------
// K4: scatter edge ids into CSR order
// ---------------------------------------------------------------------------
__global__ void scatter_kernel(const int* __restrict__ edst, int* __restrict__ cursor,
                               int* __restrict__ edge_order, int n_edge)
{
    int e = blockIdx.x * blockDim.x + threadIdx.x;
    if (e < n_edge) {
        int d = edst[e];
        int pos = atomicAdd(&cursor[d], 1);
        edge_order[pos] = e;
    }
}

// ---------------------------------------------------------------------------
// K5: per-dst softmax + weighted aggregation.  One 128-thread block per dst.
//     out[d][j] = relu( sum_e attn_e*(src_proj[s_e][j] + d0*Wd0[j] + d1*Wd1[j])
//                       + dst_proj[d][j] )          (sum_e attn_e == 1)
// ---------------------------------------------------------------------------
__global__ void __launch_bounds__(128)
aggregate_kernel(const int* __restrict__ offsets, const int* __restrict__ edge_order,
                 const int* __restrict__ esrc, const float* __restrict__ dist,
                 const float* __restrict__ src_att, const float* __restrict__ dst_att,
                 const float* __restrict__ src_proj, const float* __restrict__ dst_proj,
                 const float* __restrict__ w_att, const float* __restrict__ w_embed,
                 float* __restrict__ out)
{
    const int d = blockIdx.x;
    const int tid = threadIdx.x;
    const int begin = offsets[d];
    const int end = offsets[d + 1];

    if (begin == end) {            // empty segment -> zeros (matches reference)
        out[d * D + tid] = 0.f;
        return;
    }

    const float wa0 = w_att[128], wa1 = w_att[129];
    const float dstA = dst_att[d];

    // ---- pass 1: softmax denominator ----
    float part = 0.f;
    for (int i = begin + tid; i < end; i += 128) {
        int e = edge_order[i];
        int s = esrc[e];
        float2 dd = *reinterpret_cast<const float2*>(&dist[2 * e]);
        float sc = src_att[s] + dstA + dd.x * wa0 + dd.y * wa1;
        sc = (sc >= 0.f) ? sc : 0.2f * sc;
        part += __expf(sc);
    }
    __shared__ float red[128];
    red[tid] = part;
    __syncthreads();
    for (int off = 64; off > 0; off >>= 1) {
        if (tid < off) red[tid] += red[tid + off];
        __syncthreads();
    }
    const float inv_denom = 1.f / red[0];

    // ---- pass 2: weighted accumulation ----
    __shared__ float s_at[CHUNK];
    __shared__ int   s_s[CHUNK];
    __shared__ float s_d0[CHUNK];
    __shared__ float s_d1[CHUNK];

    const float wd0 = w_embed[128 * D + tid];
    const float wd1 = w_embed[129 * D + tid];
    float acc = 0.f;

    for (int cbase = begin; cbase < end; cbase += CHUNK) {
        int nc = min(CHUNK, end - cbase);
        for (int i = tid; i < nc; i += 128) {
            int e = edge_order[cbase + i];
            int s = esrc[e];
            float2 dd = *reinterpret_cast<const float2*>(&dist[2 * e]);
            float sc = src_att[s] + dstA + dd.x * wa0 + dd.y * wa1;
            sc = (sc >= 0.f) ? sc : 0.2f * sc;
            s_at[i] = __expf(sc) * inv_denom;
            s_s[i] = s;
            s_d0[i] = dd.x;
            s_d1[i] = dd.y;
        }
        __syncthreads();
        for (int i = 0; i < nc; ++i) {
            float at = s_at[i];
            acc += at * (src_proj[s_s[i] * D + tid] + s_d0[i] * wd0 + s_d1[i] * wd1);
        }
        __syncthreads();
    }

    float v = acc + dst_proj[d * D + tid];
    out[d * D + tid] = (v > 0.f) ? v : 0.f;
}

// ---------------------------------------------------------------------------
extern "C" void kernel_launch(void* const* d_in, const int* in_sizes, int n_in,
                              void* d_out, int out_size, void* d_ws, size_t ws_size,
                              hipStream_t stream)
{
    const float* src_feat = (const float*)d_in[0];   // [N_SRC,128]
    const int*   esrc     = (const int*)d_in[1];     // [E]
    const float* dst_feat = (const float*)d_in[2];   // [N_DST,128]
    const int*   edst     = (const int*)d_in[3];     // [E]
    const float* dist     = (const float*)d_in[4];   // [E,2]
    const float* w_att    = (const float*)d_in[5];   // [258]
    const float* w_embed  = (const float*)d_in[6];   // [258,128]

    const int n_src  = in_sizes[0] / D;
    const int n_edge = in_sizes[1];
    const int n_dst  = in_sizes[2] / D;

    // ---- workspace carve-up (all 256B-aligned) ----
    char* p = (char*)d_ws;
    auto carve = [&p](size_t bytes) {
        char* r = p;
        p += (bytes + 255) & ~size_t(255);
        return r;
    };
    float* src_proj  = (float*)carve((size_t)n_src * D * 4);
    float* dst_proj  = (float*)carve((size_t)n_dst * D * 4);
    float* src_att   = (float*)carve((size_t)n_src * 4);
    float* dst_att   = (float*)carve((size_t)n_dst * 4);
    int*   counts    = (int*)carve((size_t)n_dst * 4);
    int*   offsets   = (int*)carve((size_t)(n_dst + 1) * 4);
    int*   cursor    = (int*)carve((size_t)n_dst * 4);
    int*   edge_order= (int*)carve((size_t)n_edge * 4);
    (void)ws_size;

    // K1: node projections (src then dst)
    {
        int blocks = (n_src + NPB - 1) / NPB;
        node_proj_kernel<<<blocks, 256, 0, stream>>>(src_feat, w_embed, w_att, 0,
                                                     n_src, src_proj, src_att);
        blocks = (n_dst + NPB - 1) / NPB;
        node_proj_kernel<<<blocks, 256, 0, stream>>>(dst_feat, w_embed, w_att, 130,
                                                     n_dst, dst_proj, dst_att);
    }

    // K2: histogram
    hipMemsetAsync(counts, 0, (size_t)n_dst * 4, stream);
    hist_kernel<<<(n_edge + 255) / 256, 256, 0, stream>>>(edst, counts, n_edge);

    // K3: exclusive scan -> offsets, cursor
    scan_kernel<<<1, 1024, 0, stream>>>(counts, offsets, cursor, n_dst);

    // K4: scatter edges into CSR order
    scatter_kernel<<<(n_edge + 255) / 256, 256, 0, stream>>>(edst, cursor, edge_order,
                                                             n_edge);

    // K5: per-dst softmax + aggregation
    aggregate_kernel<<<n_dst, 128, 0, stream>>>(offsets, edge_order, esrc, dist,
                                                src_att, dst_att, src_proj, dst_proj,
                                                w_att, w_embed, (float*)d_out);
}

// Round 2
// 218.235 us; speedup vs baseline: 1.6538x; 1.6538x over previous
//
#include <hip/hip_runtime.h>
#include <hip/hip_bf16.h>

#define D 128
#define NPB 64          // nodes per block in projection kernel
#define SCAN_T 256
#define SCAN_IT 8
#define SCAN_TILE (SCAN_T * SCAN_IT)   // 2048

__device__ __forceinline__ unsigned short f32_to_bf16(float f) {
    unsigned int u = __float_as_uint(f);
    u = (u + 0x7FFFu + ((u >> 16) & 1u)) >> 16;   // RNE
    return (unsigned short)u;
}
__device__ __forceinline__ float bf16_to_f32(unsigned short h) {
    return __uint_as_float(((unsigned int)h) << 16);
}

// ---------------------------------------------------------------------------
// K1: per-node projection.  proj[n][:] = feats[n][:] @ W[wrow:wrow+128][:],
//     att[n]  = feats[n][:] . w_att[wrow:wrow+128]
// 256 threads, 64 nodes/block, register tile 8 nodes x 4 cols, float4 LDS reads
// ---------------------------------------------------------------------------
template <bool BF16OUT>
__global__ void __launch_bounds__(256)
node_proj_kernel(const float* __restrict__ feats,    // [n_nodes,128]
                 const float* __restrict__ w_embed,  // [258,128]
                 const float* __restrict__ w_att,    // [258]
                 int wrow, int n_nodes,
                 void* __restrict__ proj,            // bf16 or f32 [n_nodes,128]
                 float* __restrict__ att)            // [n_nodes]
{
    __shared__ float s_feat[NPB][D + 4];   // +4: keeps rows 16B-aligned, conflict-free
    __shared__ float s_att[NPB][4];

    const int node0 = blockIdx.x * NPB;
    const int tid = threadIdx.x;

    // stage feature tile with float4 (coalesced)
    for (int i = tid; i < NPB * D / 4; i += 256) {
        int r = i >> 5, c4 = i & 31;
        int n = node0 + r;
        float4 v = (n < n_nodes)
                 ? *reinterpret_cast<const float4*>(&feats[(size_t)n * D + c4 * 4])
                 : make_float4(0.f, 0.f, 0.f, 0.f);
        *reinterpret_cast<float4*>(&s_feat[r][c4 * 4]) = v;
    }
    __syncthreads();

    const int tx = tid & 31;   // cols 4*tx .. 4*tx+3
    const int ty = tid >> 5;   // nodes ty*8 .. ty*8+7

    float acc[8][4];
#pragma unroll
    for (int i = 0; i < 8; ++i)
#pragma unroll
        for (int j = 0; j < 4; ++j) acc[i][j] = 0.f;

    for (int k4 = 0; k4 < 32; ++k4) {
        const int k = 4 * k4;
        float4 w0 = *reinterpret_cast<const float4*>(&w_embed[(size_t)(wrow + k + 0) * D + tx * 4]);
        float4 w1 = *reinterpret_cast<const float4*>(&w_embed[(size_t)(wrow + k + 1) * D + tx * 4]);
        float4 w2 = *reinterpret_cast<const float4*>(&w_embed[(size_t)(wrow + k + 2) * D + tx * 4]);
        float4 w3 = *reinterpret_cast<const float4*>(&w_embed[(size_t)(wrow + k + 3) * D + tx * 4]);
#pragma unroll
        for (int i = 0; i < 8; ++i) {
            float4 f = *reinterpret_cast<const float4*>(&s_feat[ty * 8 + i][k]);
            acc[i][0] += f.x * w0.x + f.y * w1.x + f.z * w2.x + f.w * w3.x;
            acc[i][1] += f.x * w0.y + f.y * w1.y + f.z * w2.y + f.w * w3.y;
            acc[i][2] += f.x * w0.z + f.y * w1.z + f.z * w2.z + f.w * w3.z;
            acc[i][3] += f.x * w0.w + f.y * w1.w + f.z * w2.w + f.w * w3.w;
        }
    }

#pragma unroll
    for (int i = 0; i < 8; ++i) {
        int n = node0 + ty * 8 + i;
        if (n < n_nodes) {
            if (BF16OUT) {
                ushort4 v;
                v.x = f32_to_bf16(acc[i][0]);
                v.y = f32_to_bf16(acc[i][1]);
                v.z = f32_to_bf16(acc[i][2]);
                v.w = f32_to_bf16(acc[i][3]);
                *reinterpret_cast<ushort4*>((unsigned short*)proj + (size_t)n * D + tx * 4) = v;
            } else {
                float4 v = make_float4(acc[i][0], acc[i][1], acc[i][2], acc[i][3]);
                *reinterpret_cast<float4*>((float*)proj + (size_t)n * D + tx * 4) = v;
            }
        }
    }

    // attention scalar: 256 threads = 64 nodes x 4 k-quarters
    const int na = tid & 63;
    const int kq = tid >> 6;
    float p = 0.f;
#pragma unroll 8
    for (int k = kq * 32; k < kq * 32 + 32; ++k)
        p += s_feat[na][k] * w_att[wrow + k];
    s_att[na][kq] = p;
    __syncthreads();
    if (tid < NPB) {
        int n = node0 + tid;
        if (n < n_nodes)
            att[n] = s_att[tid][0] + s_att[tid][1] + s_att[tid][2] + s_att[tid][3];
    }
}

// ---------------------------------------------------------------------------
// K2: histogram of edge destinations
// ---------------------------------------------------------------------------
__global__ void hist_kernel(const int* __restrict__ edst, int* __restrict__ counts,
                            int n_edge)
{
    int e = blockIdx.x * blockDim.x + threadIdx.x;
    if (e < n_edge) atomicAdd(&counts[edst[e]], 1);
}

// ---------------------------------------------------------------------------
// K3a/b/c: parallel exclusive scan (block partials -> scan sums -> fixup)
// ---------------------------------------------------------------------------
__global__ void __launch_bounds__(SCAN_T)
scan_block_kernel(const int* __restrict__ counts, int* __restrict__ offsets,
                  int* __restrict__ blocksum, int n)
{
    __shared__ int s_w[4];
    const int blk = blockIdx.x, tid = threadIdx.x;
    const int lane = tid & 63, wid = tid >> 6;
    const int base = blk * SCAN_TILE + tid * SCAN_IT;

    int v[SCAN_IT];
    int tsum = 0;
#pragma unroll
    for (int i = 0; i < SCAN_IT; ++i) {
        v[i] = (base + i < n) ? counts[base + i] : 0;
        tsum += v[i];
    }
    int x = tsum;
#pragma unroll
    for (int off = 1; off < 64; off <<= 1) {
        int y = __shfl_up(x, off);
        if (lane >= off) x += y;
    }
    if (lane == 63) s_w[wid] = x;
    __syncthreads();
    if (tid == 0) {
        int a = 0;
#pragma unroll
        for (int w = 0; w < 4; ++w) { int t = s_w[w]; s_w[w] = a; a += t; }
        blocksum[blk] = a;
    }
    __syncthreads();
    int run = s_w[wid] + (x - tsum);
#pragma unroll
    for (int i = 0; i < SCAN_IT; ++i) {
        if (base + i < n) offsets[base + i] = run;
        run += v[i];
    }
}

__global__ void __launch_bounds__(64)
scan_sums_kernel(int* __restrict__ blocksum, int* __restrict__ offsets,
                 int nblk, int n)
{
    const int tid = threadIdx.x;
    int v = (tid < nblk) ? blocksum[tid] : 0;
    int x = v;
#pragma unroll
    for (int off = 1; off < 64; off <<= 1) {
        int y = __shfl_up(x, off);
        if (tid >= off) x += y;
    }
    if (tid < nblk) blocksum[tid] = x - v;   // exclusive
    if (tid == 63) offsets[n] = x;           // grand total
}

__global__ void scan_fixup_kernel(int* __restrict__ offsets, const int* __restrict__ blocksum,
                                  int* __restrict__ cursor, int n)
{
    int i = blockIdx.x * blockDim.x + threadIdx.x;
    if (i < n) {
        int o = offsets[i] + blocksum[i / SCAN_TILE];
        offsets[i] = o;
        cursor[i] = o;
    }
}

// ---------------------------------------------------------------------------
// K4: compute per-edge exp(leakyrelu(score)) and scatter packed meta into CSR
//     meta = {src_idx (bits), ew, d0, d1}
// ---------------------------------------------------------------------------
__global__ void scatter_meta_kernel(const int* __restrict__ esrc, const int* __restrict__ edst,
                                    const float* __restrict__ dist,
                                    const float* __restrict__ src_att,
                                    const float* __restrict__ dst_att,
                                    const float* __restrict__ w_att,
                                    int* __restrict__ cursor,
                                    float4* __restrict__ meta, int n_edge)
{
    int e = blockIdx.x * blockDim.x + threadIdx.x;
    if (e >= n_edge) return;
    int s = esrc[e];
    int d = edst[e];
    float2 dd = *reinterpret_cast<const float2*>(&dist[2 * (size_t)e]);
    float sc = src_att[s] + dst_att[d] + dd.x * w_att[128] + dd.y * w_att[129];
    sc = (sc >= 0.f) ? sc : 0.2f * sc;
    float ew = __expf(sc);
    int pos = atomicAdd(&cursor[d], 1);
    meta[pos] = make_float4(__int_as_float(s), ew, dd.x, dd.y);
}

// ---------------------------------------------------------------------------
// K5: wave-per-dst single-pass softmax + aggregation.
//     Each 256-thread block handles 4 dsts (one per wave). Lane holds 2 cols.
//     out[d] = relu( (Σ w_e*(srcp[s_e] ) + (Σ w_e d0)*Wd0 + (Σ w_e d1)*Wd1)/Σw
//                    + dst_proj[d] )
// ---------------------------------------------------------------------------
__global__ void __launch_bounds__(256)
aggregate_kernel(const int* __restrict__ offsets, const float4* __restrict__ meta,
                 const unsigned short* __restrict__ srcp,   // bf16 [n_src,128]
                 const float* __restrict__ dst_proj,        // f32 [n_dst,128]
                 const float* __restrict__ w_embed,         // [258,128]
                 float* __restrict__ out, int n_dst)
{
    const int wid = threadIdx.x >> 6;
    const int lane = threadIdx.x & 63;
    const int d = blockIdx.x * 4 + wid;
    if (d >= n_dst) return;

    const int c0 = 2 * lane;
    const int begin = offsets[d];
    const int end = offsets[d + 1];

    float* op = &out[(size_t)d * D + c0];
    if (begin == end) {                 // empty segment -> zeros
        op[0] = 0.f; op[1] = 0.f;
        return;
    }

    float acc0 = 0.f, acc1 = 0.f;
    float sw = 0.f, swd0 = 0.f, swd1 = 0.f;

    for (int base = begin; base < end; base += 64) {
        const int nc = min(64, end - base);
        float4 m = (lane < nc) ? meta[base + lane] : make_float4(0.f, 0.f, 0.f, 0.f);
        int s_mine = __float_as_int(m.x);
        float ew = m.y;
        sw += ew; swd0 += ew * m.z; swd1 += ew * m.w;

        for (int j = 0; j < nc; ++j) {
            float w = __shfl(ew, j);
            int s = __shfl(s_mine, j);
            unsigned int r = *reinterpret_cast<const unsigned int*>(&srcp[(size_t)s * D + c0]);
            acc0 += w * bf16_to_f32((unsigned short)(r & 0xFFFFu));
            acc1 += w * bf16_to_f32((unsigned short)(r >> 16));
        }
    }

    // wave reductions (same value lands in all lanes)
#pragma unroll
    for (int off = 32; off > 0; off >>= 1) {
        sw   += __shfl_xor(sw, off);
        swd0 += __shfl_xor(swd0, off);
        swd1 += __shfl_xor(swd1, off);
    }
    const float inv = 1.f / sw;

    const float wd0a = w_embed[128 * D + c0], wd0b = w_embed[128 * D + c0 + 1];
    const float wd1a = w_embed[129 * D + c0], wd1b = w_embed[129 * D + c0 + 1];
    const float2 dp = *reinterpret_cast<const float2*>(&dst_proj[(size_t)d * D + c0]);

    float o0 = (acc0 + swd0 * wd0a + swd1 * wd1a) * inv + dp.x;
    float o1 = (acc1 + swd0 * wd0b + swd1 * wd1b) * inv + dp.y;
    op[0] = (o0 > 0.f) ? o0 : 0.f;
    op[1] = (o1 > 0.f) ? o1 : 0.f;
}

// ---------------------------------------------------------------------------
extern "C" void kernel_launch(void* const* d_in, const int* in_sizes, int n_in,
                              void* d_out, int out_size, void* d_ws, size_t ws_size,
                              hipStream_t stream)
{
    const float* src_feat = (const float*)d_in[0];   // [N_SRC,128]
    const int*   esrc     = (const int*)d_in[1];     // [E]
    const float* dst_feat = (const float*)d_in[2];   // [N_DST,128]
    const int*   edst     = (const int*)d_in[3];     // [E]
    const float* dist     = (const float*)d_in[4];   // [E,2]
    const float* w_att    = (const float*)d_in[5];   // [258]
    const float* w_embed  = (const float*)d_in[6];   // [258,128]

    const int n_src  = in_sizes[0] / D;
    const int n_edge = in_sizes[1];
    const int n_dst  = in_sizes[2] / D;

    // ---- workspace carve-up (256B-aligned) ----
    char* p = (char*)d_ws;
    auto carve = [&p](size_t bytes) {
        char* r = p;
        p += (bytes + 255) & ~size_t(255);
        return r;
    };
    unsigned short* src_projb = (unsigned short*)carve((size_t)n_src * D * 2);  // bf16
    float* dst_proj  = (float*)carve((size_t)n_dst * D * 4);
    float* src_att   = (float*)carve((size_t)n_src * 4);
    float* dst_att   = (float*)carve((size_t)n_dst * 4);
    int*   counts    = (int*)carve((size_t)n_dst * 4);
    int*   offsets   = (int*)carve((size_t)(n_dst + 1) * 4);
    int*   cursor    = (int*)carve((size_t)n_dst * 4);
    int*   blocksum  = (int*)carve(64 * 4);
    float4* meta     = (float4*)carve((size_t)n_edge * 16);
    (void)ws_size;

    // K1: node projections (src -> bf16, dst -> f32)
    {
        int blocks = (n_src + NPB - 1) / NPB;
        node_proj_kernel<true><<<blocks, 256, 0, stream>>>(src_feat, w_embed, w_att, 0,
                                                           n_src, (void*)src_projb, src_att);
        blocks = (n_dst + NPB - 1) / NPB;
        node_proj_kernel<false><<<blocks, 256, 0, stream>>>(dst_feat, w_embed, w_att, 130,
                                                            n_dst, (void*)dst_proj, dst_att);
    }

    // K2: histogram
    hipMemsetAsync(counts, 0, (size_t)n_dst * 4, stream);
    hist_kernel<<<(n_edge + 255) / 256, 256, 0, stream>>>(edst, counts, n_edge);

    // K3: parallel exclusive scan -> offsets, cursor
    const int nblk = (n_dst + SCAN_TILE - 1) / SCAN_TILE;
    scan_block_kernel<<<nblk, SCAN_T, 0, stream>>>(counts, offsets, blocksum, n_dst);
    scan_sums_kernel<<<1, 64, 0, stream>>>(blocksum, offsets, nblk, n_dst);
    scan_fixup_kernel<<<(n_dst + 255) / 256, 256, 0, stream>>>(offsets, blocksum, cursor, n_dst);

    // K4: per-edge score + CSR scatter of packed meta
    scatter_meta_kernel<<<(n_edge + 255) / 256, 256, 0, stream>>>(esrc, edst, dist,
                                                                  src_att, dst_att, w_att,
                                                                  cursor, meta, n_edge);

    // K5: wave-per-dst aggregation
    aggregate_kernel<<<(n_dst + 3) / 4, 256, 0, stream>>>(offsets, meta, src_projb,
                                                          dst_proj, w_embed,
                                                          (float*)d_out, n_dst);
}